// Round 2
// baseline (156.144 us; speedup 1.0000x reference)
//
#include <hip/hip_runtime.h>

#define TPB 256
#define RPB 512  // rows per block = 2 rows per thread

__device__ __forceinline__ float ex2(float x) { return __builtin_amdgcn_exp2f(x); }
__device__ __forceinline__ float frcp(float x) { return __builtin_amdgcn_rcpf(x); }

// sigmoid(x) = 1/(1+exp(-x)) = 1/(1+exp2(-log2e * x))
__device__ __forceinline__ float sigm(float x) {
  return frcp(1.0f + ex2(-1.4426950408889634f * x));
}
// tanh(x) = 1 - 2/(exp2(2*log2e*x)+1)
__device__ __forceinline__ float ftanh(float x) {
  return fmaf(-2.0f, frcp(ex2(2.8853900817779268f * x) + 1.0f), 1.0f);
}

// All-scalar GRU weights (SROA-trivial; uniform loads -> SGPRs).
struct GruW {
  float w0, w1, w2, w3, w4, w5, w6, w7, w8, w9, w10, w11;   // wih[6][2]
  float u0, u1, u2, u3, u4, u5, u6, u7, u8, u9, u10, u11;   // whh[6][2]
  float br0, br1, bz0, bz1;   // bih+bhh combined for r,z gates
  float bin0, bin1, bhn0, bhn1;  // n-gate biases kept separate
};

__device__ __forceinline__ GruW load_gru(const float* __restrict__ wih,
                                         const float* __restrict__ whh,
                                         const float* __restrict__ bih,
                                         const float* __restrict__ bhh) {
  GruW g;
  g.w0 = wih[0];  g.w1 = wih[1];  g.w2 = wih[2];  g.w3 = wih[3];
  g.w4 = wih[4];  g.w5 = wih[5];  g.w6 = wih[6];  g.w7 = wih[7];
  g.w8 = wih[8];  g.w9 = wih[9];  g.w10 = wih[10]; g.w11 = wih[11];
  g.u0 = whh[0];  g.u1 = whh[1];  g.u2 = whh[2];  g.u3 = whh[3];
  g.u4 = whh[4];  g.u5 = whh[5];  g.u6 = whh[6];  g.u7 = whh[7];
  g.u8 = whh[8];  g.u9 = whh[9];  g.u10 = whh[10]; g.u11 = whh[11];
  g.br0 = bih[0] + bhh[0]; g.br1 = bih[1] + bhh[1];
  g.bz0 = bih[2] + bhh[2]; g.bz1 = bih[3] + bhh[3];
  g.bin0 = bih[4]; g.bin1 = bih[5];
  g.bhn0 = bhh[4]; g.bhn1 = bhh[5];
  return g;
}

__device__ __forceinline__ void cell(const GruW& g, float x0, float x1,
                                     float& h0, float& h1) {
  float r0 = sigm(fmaf(g.w0, x0, fmaf(g.w1, x1, fmaf(g.u0, h0, fmaf(g.u1, h1, g.br0)))));
  float r1 = sigm(fmaf(g.w2, x0, fmaf(g.w3, x1, fmaf(g.u2, h0, fmaf(g.u3, h1, g.br1)))));
  float z0 = sigm(fmaf(g.w4, x0, fmaf(g.w5, x1, fmaf(g.u4, h0, fmaf(g.u5, h1, g.bz0)))));
  float z1 = sigm(fmaf(g.w6, x0, fmaf(g.w7, x1, fmaf(g.u6, h0, fmaf(g.u7, h1, g.bz1)))));
  float gin0 = fmaf(g.w8, x0, fmaf(g.w9, x1, g.bin0));
  float gin1 = fmaf(g.w10, x0, fmaf(g.w11, x1, g.bin1));
  float ghn0 = fmaf(g.u8, h0, fmaf(g.u9, h1, g.bhn0));
  float ghn1 = fmaf(g.u10, h0, fmaf(g.u11, h1, g.bhn1));
  float n0 = ftanh(fmaf(r0, ghn0, gin0));
  float n1 = ftanh(fmaf(r1, ghn1, gin1));
  h0 = fmaf(z0, h0 - n0, n0);
  h1 = fmaf(z1, h1 - n1, n1);
}

// One full row: 7-step up GRU, obs linear, 7-step down GRU -> o[7] scalars.
__device__ __forceinline__ void row_compute(
    const float* __restrict__ xr, const GruW& up, const GruW& dn,
    float ow0, float ow1, float ow2, float ow3, float ow4, float ow5, float ow6,
    float ow7, float ow8, float ow9, float ow10, float ow11, float ow12, float ow13,
    float ob0, float ob1, float vw0, float vw1, float vb,
    float& o0, float& o1, float& o2, float& o3, float& o4, float& o5, float& o6) {
  float h0 = 0.f, h1 = 0.f;
  float hu0, hu1, hu2, hu3, hu4, hu5, hu6, hu7, hu8, hu9, hu10, hu11, hu12, hu13;
  cell(up, xr[5],  xr[12], h0, h1); hu0 = h0;  hu1 = h1;
  cell(up, xr[6],  xr[13], h0, h1); hu2 = h0;  hu3 = h1;
  cell(up, xr[7],  xr[14], h0, h1); hu4 = h0;  hu5 = h1;
  cell(up, xr[8],  xr[15], h0, h1); hu6 = h0;  hu7 = h1;
  cell(up, xr[9],  xr[16], h0, h1); hu8 = h0;  hu9 = h1;
  cell(up, xr[10], xr[17], h0, h1); hu10 = h0; hu11 = h1;
  cell(up, xr[11], xr[18], h0, h1); hu12 = h0; hu13 = h1;

  float a0 = fmaf(xr[0], ow0, fmaf(xr[1], ow1, fmaf(xr[2], ow2, fmaf(xr[3], ow3,
             fmaf(xr[4], ow4, fmaf(hu12, ow5, fmaf(hu13, ow6, ob0)))))));
  float a1 = fmaf(xr[0], ow7, fmaf(xr[1], ow8, fmaf(xr[2], ow9, fmaf(xr[3], ow10,
             fmaf(xr[4], ow11, fmaf(hu12, ow12, fmaf(hu13, ow13, ob1)))))));
  h0 = a0; h1 = a1;

  cell(dn, hu0,  hu1,  h0, h1); o0 = fmaf(vw0, h0, fmaf(vw1, h1, vb));
  cell(dn, hu2,  hu3,  h0, h1); o1 = fmaf(vw0, h0, fmaf(vw1, h1, vb));
  cell(dn, hu4,  hu5,  h0, h1); o2 = fmaf(vw0, h0, fmaf(vw1, h1, vb));
  cell(dn, hu6,  hu7,  h0, h1); o3 = fmaf(vw0, h0, fmaf(vw1, h1, vb));
  cell(dn, hu8,  hu9,  h0, h1); o4 = fmaf(vw0, h0, fmaf(vw1, h1, vb));
  cell(dn, hu10, hu11, h0, h1); o5 = fmaf(vw0, h0, fmaf(vw1, h1, vb));
  cell(dn, hu12, hu13, h0, h1); o6 = fmaf(vw0, h0, fmaf(vw1, h1, vb));
}

__global__ __launch_bounds__(TPB, 4) void rec_policy_kernel(
    const float* __restrict__ x,
    const float* __restrict__ up_wih, const float* __restrict__ up_whh,
    const float* __restrict__ up_bih, const float* __restrict__ up_bhh,
    const float* __restrict__ down_wih, const float* __restrict__ down_whh,
    const float* __restrict__ down_bih, const float* __restrict__ down_bhh,
    const float* __restrict__ obs_w, const float* __restrict__ obs_b,
    const float* __restrict__ out_w, const float* __restrict__ out_b,
    float* __restrict__ out, int B) {
  __shared__ __align__(16) float sx[RPB * 19];  // 38912 B; reused for outputs

  const int tid = threadIdx.x;
  const long base = (long)blockIdx.x * RPB;
  const int rows = min((long)RPB, (long)B - base);

  // Uniform weight loads -> s_load / SGPRs.
  const GruW up = load_gru(up_wih, up_whh, up_bih, up_bhh);
  const GruW dn = load_gru(down_wih, down_whh, down_bih, down_bhh);
  const float ow0 = obs_w[0], ow1 = obs_w[1], ow2 = obs_w[2], ow3 = obs_w[3],
              ow4 = obs_w[4], ow5 = obs_w[5], ow6 = obs_w[6], ow7 = obs_w[7],
              ow8 = obs_w[8], ow9 = obs_w[9], ow10 = obs_w[10], ow11 = obs_w[11],
              ow12 = obs_w[12], ow13 = obs_w[13];
  const float ob0 = obs_b[0], ob1 = obs_b[1];
  const float vw0 = out_w[0], vw1 = out_w[1], vb = out_b[0];

  if (rows == RPB) {
    // ---- coalesced float4 input staging: 512*19/4 = 2432 vec4 ----
    {
      const float4* src = (const float4*)(x + base * 19);
      float4* dst = (float4*)sx;
      for (int i = tid; i < RPB * 19 / 4; i += TPB) dst[i] = src[i];
    }
    __syncthreads();

    // ---- two independent rows per thread (ILP) ----
    const float* xa = sx + tid * 19;          // stride 19 (odd): <=2-way bank alias = free
    const float* xb = sx + (tid + TPB) * 19;
    float ao0, ao1, ao2, ao3, ao4, ao5, ao6;
    float bo0, bo1, bo2, bo3, bo4, bo5, bo6;
    row_compute(xa, up, dn, ow0, ow1, ow2, ow3, ow4, ow5, ow6, ow7, ow8, ow9,
                ow10, ow11, ow12, ow13, ob0, ob1, vw0, vw1, vb,
                ao0, ao1, ao2, ao3, ao4, ao5, ao6);
    row_compute(xb, up, dn, ow0, ow1, ow2, ow3, ow4, ow5, ow6, ow7, ow8, ow9,
                ow10, ow11, ow12, ow13, ob0, ob1, vw0, vw1, vb,
                bo0, bo1, bo2, bo3, bo4, bo5, bo6);

    // ---- reuse sx as output staging after barrier ----
    __syncthreads();
    float* soa = sx + tid * 7;
    soa[0] = ao0; soa[1] = ao1; soa[2] = ao2; soa[3] = ao3;
    soa[4] = ao4; soa[5] = ao5; soa[6] = ao6;
    float* sob = sx + (tid + TPB) * 7;
    sob[0] = bo0; sob[1] = bo1; sob[2] = bo2; sob[3] = bo3;
    sob[4] = bo4; sob[5] = bo5; sob[6] = bo6;
    __syncthreads();

    // ---- coalesced float4 store: 512*7/4 = 896 vec4 ----
    float4* dst = (float4*)(out + base * 7);
    const float4* s4 = (const float4*)sx;
    for (int i = tid; i < RPB * 7 / 4; i += TPB) dst[i] = s4[i];
  } else {
    // ---- tail block (not taken for B=1048576): scalar, correct ----
    for (int i = tid; i < rows * 19; i += TPB) sx[i] = x[base * 19 + i];
    __syncthreads();
    for (int r = tid; r < rows; r += TPB) {
      const float* xr = sx + r * 19;
      float o0, o1, o2, o3, o4, o5, o6;
      row_compute(xr, up, dn, ow0, ow1, ow2, ow3, ow4, ow5, ow6, ow7, ow8, ow9,
                  ow10, ow11, ow12, ow13, ob0, ob1, vw0, vw1, vb,
                  o0, o1, o2, o3, o4, o5, o6);
      float* po = out + (base + r) * 7;
      po[0] = o0; po[1] = o1; po[2] = o2; po[3] = o3;
      po[4] = o4; po[5] = o5; po[6] = o6;
    }
  }
}

extern "C" void kernel_launch(void* const* d_in, const int* in_sizes, int n_in,
                              void* d_out, int out_size, void* d_ws, size_t ws_size,
                              hipStream_t stream) {
  const float* x        = (const float*)d_in[0];
  const float* up_wih   = (const float*)d_in[1];
  const float* up_whh   = (const float*)d_in[2];
  const float* up_bih   = (const float*)d_in[3];
  const float* up_bhh   = (const float*)d_in[4];
  const float* down_wih = (const float*)d_in[5];
  const float* down_whh = (const float*)d_in[6];
  const float* down_bih = (const float*)d_in[7];
  const float* down_bhh = (const float*)d_in[8];
  const float* obs_w    = (const float*)d_in[9];
  const float* obs_b    = (const float*)d_in[10];
  const float* out_w    = (const float*)d_in[11];
  const float* out_b    = (const float*)d_in[12];
  float* out = (float*)d_out;

  const int B = in_sizes[0] / 19;
  const int blocks = (B + RPB - 1) / RPB;
  rec_policy_kernel<<<blocks, TPB, 0, stream>>>(
      x, up_wih, up_whh, up_bih, up_bhh, down_wih, down_whh, down_bih, down_bhh,
      obs_w, obs_b, out_w, out_b, out, B);
}